// Round 2
// 938.417 us; speedup vs baseline: 1.0607x; 1.0607x over previous
//
#include <hip/hip_runtime.h>
#include <hip/hip_bf16.h>
#include <cstdint>
#include <cstddef>

// Shapes fixed by the problem
#define BATCH 2
#define SEQ 2048
#define NH 16
#define DH 64
#define DM 1024
#define MTOT 4096  // BATCH*SEQ

typedef __attribute__((ext_vector_type(8))) short short8;
typedef __attribute__((ext_vector_type(4))) float f32x4;

#define MFMA16(a, b, c) __builtin_amdgcn_mfma_f32_16x16x32_bf16((a), (b), (c), 0, 0, 0)

__device__ __forceinline__ unsigned short f2bf(float f) {
  unsigned int u = __builtin_bit_cast(unsigned int, f);
  u += 0x7fffu + ((u >> 16) & 1u);   // RNE; inputs are finite
  return (unsigned short)(u >> 16);
}

// ---------------- input cast: q,k,v fp32 -> bf16 ----------------
__global__ __launch_bounds__(256) void cvt_x(const float* __restrict__ q,
                                             const float* __restrict__ k,
                                             const float* __restrict__ v,
                                             unsigned short* __restrict__ dst) {
  const float* srcs[3] = {q, k, v};
  const float* s = srcs[blockIdx.y];
  unsigned short* d = dst + (size_t)blockIdx.y * (MTOT * DM);
  int i = blockIdx.x * 256 + threadIdx.x;
  if (i < (MTOT * DM / 4)) {
    float4 f = ((const float4*)s)[i];
    ushort4 o;
    o.x = f2bf(f.x); o.y = f2bf(f.y); o.z = f2bf(f.z); o.w = f2bf(f.w);
    ((ushort4*)d)[i] = o;
  }
}

// ---------------- weight cast + transpose: W[k][n] -> WT[n][k] bf16 ----------------
__global__ __launch_bounds__(256) void cvt_w(const float* __restrict__ w0,
                                             const float* __restrict__ w1,
                                             const float* __restrict__ w2,
                                             const float* __restrict__ w3,
                                             unsigned short* __restrict__ dst) {
  const float* srcs[4] = {w0, w1, w2, w3};
  const float* src = srcs[blockIdx.z];
  unsigned short* d = dst + (size_t)blockIdx.z * (DM * DM);
  __shared__ float t[32][33];
  int tx = threadIdx.x & 31, ty = threadIdx.x >> 5;  // ty 0..7
  int k0 = blockIdx.y * 32, n0 = blockIdx.x * 32;
#pragma unroll
  for (int r = 0; r < 32; r += 8) t[ty + r][tx] = src[(k0 + ty + r) * DM + n0 + tx];
  __syncthreads();
#pragma unroll
  for (int r = 0; r < 32; r += 8) d[(n0 + ty + r) * DM + k0 + tx] = f2bf(t[tx][ty + r]);
}

// ---------------- 128x64-tile bf16 MFMA GEMM ----------------
// C[m,n] = sum_k A[m,k]*Bt[n,k] + bias[n]
// KIND 0: QKV fused via blockIdx.z (z=0 Q, z=1 K -> bf16 head layout; z=2 V -> bf16 head-T layout)
//         A = Abase + z*MTOT*DM ; Bt = Wbase + z*DM*DM ; out = outbase + z*MTOT*DM (ushort)
// KIND 1: plain fp32 out [m*DM+n] (output projection)
// grid (M/128, DM/64 [, 3]); block 256 (4 waves, each 32 rows x 64 cols)
template <int KIND>
__global__ __launch_bounds__(256) void gemm_t64(const unsigned short* __restrict__ Abase,
                                                const unsigned short* __restrict__ Wbase,
                                                const float* __restrict__ b0,
                                                const float* __restrict__ b1,
                                                const float* __restrict__ b2,
                                                void* __restrict__ outbase) {
  const int z = (KIND == 0) ? blockIdx.z : 0;
  const unsigned short* A = Abase + (size_t)z * MTOT * DM;
  const unsigned short* Bt = Wbase + (size_t)z * DM * DM;
  const float* bias = (KIND == 1) ? b0 : (z == 0 ? b0 : (z == 1 ? b1 : b2));

  __shared__ unsigned short As[128 * 32];
  __shared__ unsigned short Bs[64 * 32];
  int tid = threadIdx.x, lane = tid & 63;
  int w = tid >> 6;                      // wave 0..3 -> rows w*32..w*32+31
  int quad = lane >> 4, l15 = lane & 15;
  int m0 = blockIdx.x * 128, n0 = blockIdx.y * 64;
  f32x4 acc[2][4] = {};

  int r0 = tid >> 2;          // 0..63
  int c0 = (tid & 3) * 8;     // ushort col within 32-wide K slab
  const uint4* ga0 = (const uint4*)(A + (size_t)(m0 + r0) * DM + c0);
  const uint4* ga1 = (const uint4*)(A + (size_t)(m0 + 64 + r0) * DM + c0);
  const uint4* gb  = (const uint4*)(Bt + (size_t)(n0 + r0) * DM + c0);

  for (int k0 = 0; k0 < DM; k0 += 32) {
    uint4 va0 = ga0[k0 >> 3];
    uint4 va1 = ga1[k0 >> 3];
    uint4 vb  = gb[k0 >> 3];
    __syncthreads();
    *(uint4*)(As + tid * 8) = va0;
    *(uint4*)(As + 2048 + tid * 8) = va1;
    *(uint4*)(Bs + tid * 8) = vb;
    __syncthreads();
    short8 af[2], bfr[4];
#pragma unroll
    for (int i = 0; i < 2; i++)
      af[i] = *(const short8*)(As + (w * 32 + i * 16 + l15) * 32 + quad * 8);
#pragma unroll
    for (int j = 0; j < 4; j++)
      bfr[j] = *(const short8*)(Bs + (j * 16 + l15) * 32 + quad * 8);
#pragma unroll
    for (int i = 0; i < 2; i++)
#pragma unroll
      for (int j = 0; j < 4; j++) acc[i][j] = MFMA16(af[i], bfr[j], acc[i][j]);
  }

  float bvals[4];
#pragma unroll
  for (int j = 0; j < 4; j++) bvals[j] = bias[n0 + j * 16 + l15];
#pragma unroll
  for (int i = 0; i < 2; i++) {
#pragma unroll
    for (int j = 0; j < 4; j++) {
#pragma unroll
      for (int r = 0; r < 4; r++) {
        int m = m0 + w * 32 + i * 16 + quad * 4 + r;
        int n = n0 + j * 16 + l15;
        float v = acc[i][j][r] + bvals[j];
        if (KIND == 1) {
          ((float*)outbase)[(size_t)m * DM + n] = v;
        } else {
          unsigned short* dq = (unsigned short*)outbase + (size_t)z * MTOT * DM;
          if (z < 2) {
            // head layout: dst[((b*16+h)*SEQ + s)*DH + d]
            dq[(((size_t)((m >> 11) * 16 + (n >> 6)) * SEQ + (m & 2047)) * DH) + (n & 63)] = f2bf(v);
          } else {
            // head-T layout: dst[((b*16+h)*DH + d)*SEQ + s]
            dq[(((size_t)((m >> 11) * 16 + (n >> 6)) * DH + (n & 63)) * SEQ) + (m & 2047)] = f2bf(v);
          }
        }
      }
    }
  }
}

// ---------------- fused attention ----------------
// grid (32 = B*H, 64 = SEQ/32); block 128 (2 waves, 16 Q-rows each). No barriers,
// per-wave LDS tiles -> small blocks raise occupancy (grid was the old cap at 16 waves/CU).
// Pass 1: row sums of exp(s). Pass 2: recompute s, stage fp32 P tile in LDS,
// write attn as coalesced nontemporal dwordx4, derive bf16 PV A-frag from same tile.
__global__ __launch_bounds__(128) void attn_fused(const unsigned short* __restrict__ Qh,
                                                  const unsigned short* __restrict__ Kh,
                                                  const unsigned short* __restrict__ VhT,
                                                  float* __restrict__ attn_out,
                                                  unsigned short* __restrict__ ctx) {
  int bh = blockIdx.x;
  int q0 = blockIdx.y * 32;
  int tid = threadIdx.x, w = tid >> 6, lane = tid & 63;
  int quad = lane >> 4, l15 = lane & 15;
  int qrow = q0 + w * 16;
  const unsigned short* Qb = Qh + ((size_t)bh * SEQ + qrow) * DH;
  const unsigned short* Kb = Kh + (size_t)bh * SEQ * DH;
  const unsigned short* Vb = VhT + (size_t)bh * DH * SEQ;

  short8 aq0 = *(const short8*)(Qb + l15 * DH + quad * 8);
  short8 aq1 = *(const short8*)(Qb + l15 * DH + 32 + quad * 8);

  // ---- pass 1: row sums of exp(scores), 32 cols/iter for load ILP ----
  float part[4] = {0.f, 0.f, 0.f, 0.f};
  for (int kt = 0; kt < SEQ; kt += 32) {
    const unsigned short* kp = Kb + (size_t)(kt + l15) * DH + quad * 8;
    short8 k00 = *(const short8*)(kp);
    short8 k01 = *(const short8*)(kp + 32);
    short8 k10 = *(const short8*)(kp + 16 * DH);
    short8 k11 = *(const short8*)(kp + 16 * DH + 32);
    f32x4 s0 = {0.f, 0.f, 0.f, 0.f}, s1 = {0.f, 0.f, 0.f, 0.f};
    s0 = MFMA16(aq0, k00, s0);
    s0 = MFMA16(aq1, k01, s0);
    s1 = MFMA16(aq0, k10, s1);
    s1 = MFMA16(aq1, k11, s1);
#pragma unroll
    for (int r = 0; r < 4; r++)
      part[r] += __expf(s0[r] * 0.125f) + __expf(s1[r] * 0.125f);
  }
#pragma unroll
  for (int off = 1; off < 16; off <<= 1) {
#pragma unroll
    for (int r = 0; r < 4; r++) part[r] += __shfl_xor(part[r], off, 64);
  }
  float inv[4];
#pragma unroll
  for (int r = 0; r < 4; r++) inv[r] = 1.0f / part[r];

  // ---- pass 2: attn write (LDS-staged, coalesced) + PV ----
  // per-wave fp32 P tile [16 rows][36 floats]: stride 36 -> 2-way bank alias (free),
  // rows stay 16B-aligned (144 B)
  __shared__ float plds[2][16 * 36];
  float* pl = &plds[w][0];
  f32x4 cacc0 = {}, cacc1 = {}, cacc2 = {}, cacc3 = {};
  float* arow = attn_out + ((size_t)bh * SEQ + qrow) * SEQ;

  for (int kt = 0; kt < SEQ; kt += 32) {
    // V loads are independent of the QK/exp chain -> issue first
    const unsigned short* vp = Vb + (size_t)l15 * SEQ + kt + quad * 8;
    short8 bv0 = *(const short8*)(vp);
    short8 bv1 = *(const short8*)(vp + 16 * SEQ);
    short8 bv2 = *(const short8*)(vp + 32 * SEQ);
    short8 bv3 = *(const short8*)(vp + 48 * SEQ);

    const unsigned short* kp = Kb + (size_t)(kt + l15) * DH + quad * 8;
    short8 k00 = *(const short8*)(kp);
    short8 k01 = *(const short8*)(kp + 32);
    short8 k10 = *(const short8*)(kp + 16 * DH);
    short8 k11 = *(const short8*)(kp + 16 * DH + 32);
    f32x4 s0 = {0.f, 0.f, 0.f, 0.f}, s1 = {0.f, 0.f, 0.f, 0.f};
    s0 = MFMA16(aq0, k00, s0);
    s0 = MFMA16(aq1, k01, s0);
    s1 = MFMA16(aq0, k10, s1);
    s1 = MFMA16(aq1, k11, s1);
#pragma unroll
    for (int r = 0; r < 4; r++) {
      float p0 = __expf(s0[r] * 0.125f) * inv[r];
      float p1 = __expf(s1[r] * 0.125f) * inv[r];
      pl[(quad * 4 + r) * 36 + l15] = p0;
      pl[(quad * 4 + r) * 36 + 16 + l15] = p1;
    }
    // same-wave DS ordering: the writes above are visible to the reads below
    // coalesced attn store: 8 rows x 32 cols per read, two nontemporal dwordx4 stores
    {
      int rr = lane >> 3, cc = (lane & 7) * 4;
      f32x4 row0 = *(const f32x4*)(pl + rr * 36 + cc);
      f32x4 row1 = *(const f32x4*)(pl + (rr + 8) * 36 + cc);
      __builtin_nontemporal_store(row0, (f32x4*)(arow + (size_t)rr * SEQ + kt + cc));
      __builtin_nontemporal_store(row1, (f32x4*)(arow + (size_t)(rr + 8) * SEQ + kt + cc));
    }
    // PV A-frag from the same fp32 tile
    f32x4 pf0 = *(const f32x4*)(pl + l15 * 36 + quad * 8);
    f32x4 pf1 = *(const f32x4*)(pl + l15 * 36 + quad * 8 + 4);
    short8 pa;
    pa[0] = (short)f2bf(pf0[0]); pa[1] = (short)f2bf(pf0[1]);
    pa[2] = (short)f2bf(pf0[2]); pa[3] = (short)f2bf(pf0[3]);
    pa[4] = (short)f2bf(pf1[0]); pa[5] = (short)f2bf(pf1[1]);
    pa[6] = (short)f2bf(pf1[2]); pa[7] = (short)f2bf(pf1[3]);
    cacc0 = MFMA16(pa, bv0, cacc0);
    cacc1 = MFMA16(pa, bv1, cacc1);
    cacc2 = MFMA16(pa, bv2, cacc2);
    cacc3 = MFMA16(pa, bv3, cacc3);
  }

  int b = bh >> 4, h = bh & 15;
  f32x4 cc[4] = {cacc0, cacc1, cacc2, cacc3};
#pragma unroll
  for (int dt = 0; dt < 4; dt++) {
#pragma unroll
    for (int r = 0; r < 4; r++) {
      int m = b * SEQ + qrow + quad * 4 + r;
      int c = h * DH + dt * 16 + l15;
      ctx[(size_t)m * DM + c] = f2bf(cc[dt][r]);
    }
  }
}

// ---------------- host launch ----------------
extern "C" void kernel_launch(void* const* d_in, const int* in_sizes, int n_in,
                              void* d_out, int out_size, void* d_ws, size_t ws_size,
                              hipStream_t stream) {
  const float* q  = (const float*)d_in[0];
  const float* k  = (const float*)d_in[1];
  const float* v  = (const float*)d_in[2];
  // d_in[3] = mask: accepted but unused (as in reference)
  const float* wq = (const float*)d_in[4];
  const float* bq = (const float*)d_in[5];
  const float* wk = (const float*)d_in[6];
  const float* bk = (const float*)d_in[7];
  const float* wv = (const float*)d_in[8];
  const float* bv = (const float*)d_in[9];
  const float* wo = (const float*)d_in[10];
  const float* bo = (const float*)d_in[11];

  char* ws = (char*)d_ws;
  // ws layout (bytes):
  //   0        : xb   (q,k,v bf16)   3 * 8 MB
  //   24 MB    : wT   (4 transposed bf16 weights) 4 * 2 MB
  //   32 MB    : QH   bf16 [BH,S,64]  8 MB
  //   40 MB    : KH   bf16 [BH,S,64]  8 MB   (= QH + 1*MTOT*DM elems)
  //   48 MB    : VT   bf16 [BH,64,S]  8 MB   (= QH + 2*MTOT*DM elems)
  //   56 MB    : CTX  bf16 [M,DM]     8 MB      -> total 64 MB
  unsigned short* xb  = (unsigned short*)(ws);
  unsigned short* wT  = (unsigned short*)(ws + (size_t)24 * 1024 * 1024);
  unsigned short* QH  = (unsigned short*)(ws + (size_t)32 * 1024 * 1024);
  unsigned short* KH  = (unsigned short*)(ws + (size_t)40 * 1024 * 1024);
  unsigned short* VT  = (unsigned short*)(ws + (size_t)48 * 1024 * 1024);
  unsigned short* CTX = (unsigned short*)(ws + (size_t)56 * 1024 * 1024);

  float* out_proj = (float*)d_out;                       // [B,S,DM]
  float* attn_out = (float*)d_out + (size_t)MTOT * DM;   // [B,H,S,S]

  cvt_x<<<dim3(MTOT * DM / 4 / 256, 3), 256, 0, stream>>>(q, k, v, xb);
  cvt_w<<<dim3(32, 32, 4), 256, 0, stream>>>(wq, wk, wv, wo, wT);

  // fused Q/K/V projections: grid (32,16,3) = 1536 WGs -> 6 WG/CU
  gemm_t64<0><<<dim3(32, 16, 3), 256, 0, stream>>>(xb, wT, bq, bk, bv, QH);

  // attention: 2048 WGs of 2 waves -> up to ~24+ waves/CU
  attn_fused<<<dim3(BATCH * NH, SEQ / 32), 128, 0, stream>>>(QH, KH, VT, attn_out, CTX);

  // output projection -> fp32 d_out: grid (32,16) = 512 WGs -> 2 WG/CU
  gemm_t64<1><<<dim3(32, 16), 256, 0, stream>>>(CTX, wT + (size_t)3 * DM * DM, bo, bo, bo, out_proj);
}